// Round 1
// baseline (451.592 us; speedup 1.0000x reference)
//
#include <hip/hip_runtime.h>
#include <math.h>

#define PI_F      3.141592653f
#define TWO_PI_F  6.283185306f
#define HALF_PI_F 1.5707963265f
#define IOU_THR_F 0.1f

__device__ __forceinline__ float limit_period_f(float v) {
    return v - floorf(v / TWO_PI_F + 0.5f) * TWO_PI_F;
}

// ---------------- Kernel 1: per-box prep (lo/hi/vol/dir) ----------------
__global__ void prep_kernel(const float* __restrict__ boxes, int n,
                            float* __restrict__ lox, float* __restrict__ loy, float* __restrict__ loz,
                            float* __restrict__ hix, float* __restrict__ hiy, float* __restrict__ hiz,
                            float* __restrict__ vol, float* __restrict__ dir) {
    int j = blockIdx.x * blockDim.x + threadIdx.x;
    if (j >= n) return;
    float b0 = boxes[j*7+0], b1 = boxes[j*7+1], b2 = boxes[j*7+2];
    float b3 = boxes[j*7+3], b4 = boxes[j*7+4], b5 = boxes[j*7+5];
    float b6 = boxes[j*7+6];
    // reference: c = boxes[:, :3]; d = boxes[:, [5,4,3]] = (l, w, h)
    lox[j] = b0 - b5*0.5f; hix[j] = b0 + b5*0.5f;
    loy[j] = b1 - b4*0.5f; hiy[j] = b1 + b4*0.5f;
    loz[j] = b2 - b3*0.5f; hiz[j] = b2 + b3*0.5f;
    vol[j] = (b5*b4)*b3;                   // d.prod(-1) order: l*w*h
    dir[j] = limit_period_f(b6);
}

// ---------------- Kernel 2: adjacency bit-matrix (iou > 0.1) ----------------
__global__ void adj_kernel(const float* __restrict__ lox, const float* __restrict__ loy,
                           const float* __restrict__ loz, const float* __restrict__ hix,
                           const float* __restrict__ hiy, const float* __restrict__ hiz,
                           const float* __restrict__ vol,
                           unsigned long long* __restrict__ adj, int n, int words) {
    int i = blockIdx.x;
    float lxi = lox[i], lyi = loy[i], lzi = loz[i];
    float hxi = hix[i], hyi = hiy[i], hzi = hiz[i];
    float vi  = vol[i];
    int tid = threadIdx.x;              // 256 threads = 4 waves
    int ntile = (n + 255) >> 8;
    for (int t = 0; t < ntile; ++t) {
        int j = (t << 8) + tid;
        bool pred = false;
        if (j < n) {
            float ix = fminf(hxi, hix[j]) - fmaxf(lxi, lox[j]); ix = fmaxf(ix, 0.0f);
            float iy = fminf(hyi, hiy[j]) - fmaxf(lyi, loy[j]); iy = fmaxf(iy, 0.0f);
            float iz = fminf(hzi, hiz[j]) - fmaxf(lzi, loz[j]); iz = fmaxf(iz, 0.0f);
            float inter = (ix*iy)*iz;
            float u = fmaxf(vi + vol[j] - inter, 1e-8f);
            pred = (inter / u) > IOU_THR_F;
        }
        unsigned long long m = __ballot(pred);
        if ((tid & 63) == 0) {
            int wi = j >> 6;
            if (wi < words) adj[(size_t)i * words + wi] = m;
        }
    }
}

// ---------------- Kernel 3: sequential greedy clustering (single wave) ----------------
__global__ void cluster_kernel(const unsigned long long* __restrict__ adj,
                               int* __restrict__ indices, int* __restrict__ nclust,
                               int n, int words) {
    __shared__ unsigned short idxS[4096];
    int lane = threadIdx.x;  // 64 threads = 1 wave
    for (int j = lane; j < n; j += 64) idxS[j] = 0;
    // lane t owns covered-word t (bits j in [t*64, t*64+64))
    unsigned long long covered = ~0ull;
    if (lane < words) {
        int validBits = n - lane * 64;
        covered = (validBits >= 64) ? 0ull
                : ((validBits <= 0) ? ~0ull : (~0ull << validBits));
    }
    int cid = 1;
    while (true) {
        unsigned long long notc = ~covered;
        int cand = (notc != 0ull) ? (lane*64 + (int)__ffsll(notc) - 1) : 0x7fffffff;
        for (int o = 32; o > 0; o >>= 1) {
            int other = __shfl_xor(cand, o);
            cand = min(cand, other);
        }
        if (cand == 0x7fffffff) break;
        int seed = cand;
        unsigned long long a = (lane < words) ? adj[(size_t)seed * words + lane] : 0ull;
        covered |= a;
        while (a) {
            int b = (int)__ffsll(a) - 1;
            a &= a - 1;
            idxS[lane*64 + b] = (unsigned short)cid;   // overwrite = reference semantics
        }
        cid++;
    }
    for (int j = lane; j < n; j += 64) indices[j] = (int)idxS[j];
    if (lane == 0) *nclust = cid - 1;
}

// ---------------- Kernel 4: per-cluster fusion ----------------
__global__ void fusion_kernel(const float* __restrict__ boxes,
                              const float* __restrict__ scores,
                              const int* __restrict__ indices,
                              const float* __restrict__ dir,
                              const int* __restrict__ nclust,
                              float* __restrict__ fused,
                              float* __restrict__ sfused,
                              int* __restrict__ validArr, int n) {
    int i = blockIdx.x;           // output row; cluster id = i+1
    int tid = threadIdx.x;        // 256
    int cid = i + 1;
    if (cid > *nclust) {
        if (tid < 7) fused[i*7+tid] = 0.0f;
        if (tid == 0) { sfused[i] = 0.0f; validArr[i] = 0; }
        return;
    }
    __shared__ unsigned short js[4096];
    __shared__ float ms[4096];
    __shared__ int scanBuf[256];
    __shared__ int totalS;
    int chunk = (n + 255) >> 8;   // 16 for n=4096
    int start = tid * chunk;
    // pass 1: count
    int cnt = 0;
    for (int k = 0; k < chunk; ++k) {
        int j = start + k;
        if (j < n && indices[j] == cid) cnt++;
    }
    scanBuf[tid] = cnt;
    __syncthreads();
    for (int o = 1; o < 256; o <<= 1) {
        int v = scanBuf[tid];
        int add = (tid >= o) ? scanBuf[tid - o] : 0;
        __syncthreads();
        scanBuf[tid] = v + add;
        __syncthreads();
    }
    int excl = scanBuf[tid] - cnt;
    if (tid == 255) totalS = scanBuf[255];
    // pass 2: ordered write (deterministic, ascending j)
    int pos = excl;
    for (int k = 0; k < chunk; ++k) {
        int j = start + k;
        if (j < n && indices[j] == cid) js[pos++] = (unsigned short)j;
    }
    __syncthreads();
    int m = totalS;
    if (m == 0) {
        if (tid < 7) fused[i*7+tid] = 0.0f;
        if (tid == 0) { sfused[i] = 0.0f; validArr[i] = 0; }
        return;
    }
    for (int k = tid; k < m; k += 256) ms[k] = scores[js[k]];
    __syncthreads();
    if (tid == 0) {
        // s_sum and argmax (first occurrence of max; js ascending + strict >)
        float ssum = 0.0f, smax = -1e30f; int refj = js[0];
        for (int k = 0; k < m; ++k) {
            float s = ms[k];
            ssum += s;
            if (s > smax) { smax = s; refj = js[k]; }
        }
        float refdir = dir[refj];
        float denom = fmaxf(ssum, 1e-12f);
        // score_gt + weighted center/dim sums
        float sgt = 0.0f;
        float cd0=0,cd1=0,cd2=0,cd3=0,cd4=0,cd5=0;
        for (int k = 0; k < m; ++k) {
            int j = js[k];
            float s = ms[k];
            float d = fabsf(dir[j] - refdir);
            if (d > PI_F) d = TWO_PI_F - d;
            if (d > HALF_PI_F) sgt += s;
            float w = s / denom;
            cd0 += w * boxes[j*7+0];
            cd1 += w * boxes[j*7+1];
            cd2 += w * boxes[j*7+2];
            cd3 += w * boxes[j*7+3];
            cd4 += w * boxes[j*7+4];
            cd5 += w * boxes[j*7+5];
        }
        float sle = ssum - sgt;
        bool flipGt = (sgt <= sle);        // flip = flipGt ? gt : !gt
        float ssin = 0.0f, scos = 0.0f;
        for (int k = 0; k < m; ++k) {
            int j = js[k];
            float s = ms[k];
            float dj = dir[j];
            float d = fabsf(dj - refdir);
            if (d > PI_F) d = TWO_PI_F - d;
            bool gt = d > HALF_PI_F;
            bool flip = flipGt ? gt : !gt;
            float adj_d = limit_period_f(dj + (flip ? PI_F : 0.0f));
            float w = s / denom;
            ssin += sinf(adj_d) * w;
            scos += cosf(adj_d) * w;
        }
        float theta = atan2f(ssin, scos);
        // s_fused: sort member scores descending, sum s_k^(k+1)
        for (int k = 1; k < m; ++k) {
            float key = ms[k]; int p = k - 1;
            while (p >= 0 && ms[p] < key) { ms[p+1] = ms[p]; --p; }
            ms[p+1] = key;
        }
        float sf = 0.0f;
        for (int k = 0; k < m; ++k) sf += powf(ms[k], (float)(k+1));
        sf = fminf(sf, 1.0f);
        // corners range check (z never checked; 4 distinct xy corners)
        float c_ = cosf(theta), s_ = sinf(theta);
        float wdim = cd4, ldim = cd5;
        const float xs[4]  = {0.5f, 0.5f, -0.5f, -0.5f};
        const float ys_[4] = {-0.5f, 0.5f, 0.5f, -0.5f};
        bool inr = true;
        for (int c = 0; c < 4; ++c) {
            float cx = ldim * xs[c], cy = wdim * ys_[c];
            float rx = cx*c_ - cy*s_ + cd0;
            float ry = cx*s_ + cy*c_ + cd1;
            inr = inr && (rx > -140.8f) && (rx < 140.8f) && (ry > -40.0f) && (ry < 40.0f);
        }
        fused[i*7+0]=cd0; fused[i*7+1]=cd1; fused[i*7+2]=cd2;
        fused[i*7+3]=cd3; fused[i*7+4]=cd4; fused[i*7+5]=cd5;
        fused[i*7+6]=theta;
        sfused[i] = sf;
        validArr[i] = inr ? 1 : 0;
    }
}

// ---------------- Kernel 5: cumsum + gated output writes ----------------
__global__ void finalize_kernel(const float* __restrict__ fused,
                                const float* __restrict__ sfused,
                                const int* __restrict__ validArr,
                                const int* __restrict__ indices,
                                float* __restrict__ out, int n) {
    __shared__ int newidS[4096];
    __shared__ unsigned char validS[4096];
    __shared__ int scanBuf[1024];
    int tid = threadIdx.x;  // 1024
    int per = (n + 1023) >> 10;  // 4
    int base = tid * per;
    int v[8];
    int sum = 0;
    for (int k = 0; k < per && k < 8; ++k) {
        int j = base + k;
        int vv = (j < n) ? validArr[j] : 0;
        v[k] = vv; sum += vv;
    }
    scanBuf[tid] = sum;
    __syncthreads();
    for (int o = 1; o < 1024; o <<= 1) {
        int val = scanBuf[tid];
        int add = (tid >= o) ? scanBuf[tid - o] : 0;
        __syncthreads();
        scanBuf[tid] = val + add;
        __syncthreads();
    }
    int run = scanBuf[tid] - sum;
    for (int k = 0; k < per && k < 8; ++k) {
        int j = base + k;
        if (j < n) { run += v[k]; newidS[j] = run; validS[j] = (unsigned char)v[k]; }
    }
    __syncthreads();
    float* boxesO  = out;
    float* scoresO = out + (size_t)7*n;
    float* validO  = out + (size_t)8*n;
    float* idxO    = out + (size_t)9*n;
    for (int j = tid; j < n; j += 1024) {
        int vv = validS[j];
        #pragma unroll
        for (int k = 0; k < 7; ++k)
            boxesO[j*7+k] = vv ? fused[j*7+k] : 0.0f;
        scoresO[j] = vv ? sfused[j] : 0.0f;
        validO[j]  = vv ? 1.0f : 0.0f;
        int ind = indices[j];
        int safe = ind - 1; if (safe < 0) safe = 0;
        bool nv = (ind > 0) && (validS[safe] != 0);
        idxO[j] = nv ? (float)newidS[safe] : 0.0f;
    }
}

extern "C" void kernel_launch(void* const* d_in, const int* in_sizes, int n_in,
                              void* d_out, int out_size, void* d_ws, size_t ws_size,
                              hipStream_t stream) {
    const float* boxes  = (const float*)d_in[0];
    const float* scores = (const float*)d_in[1];
    int n = in_sizes[0] / 7;           // 4096
    int words = (n + 63) >> 6;         // 64

    char* ws = (char*)d_ws;
    size_t nf = (size_t)n * sizeof(float);
    size_t off = 0;
    float* lox = (float*)(ws + off); off += nf;
    float* loy = (float*)(ws + off); off += nf;
    float* loz = (float*)(ws + off); off += nf;
    float* hix = (float*)(ws + off); off += nf;
    float* hiy = (float*)(ws + off); off += nf;
    float* hiz = (float*)(ws + off); off += nf;
    float* vol = (float*)(ws + off); off += nf;
    float* dir = (float*)(ws + off); off += nf;
    off = (off + 7) & ~(size_t)7;
    unsigned long long* adj = (unsigned long long*)(ws + off);
    off += (size_t)n * words * sizeof(unsigned long long);
    int* indices = (int*)(ws + off); off += (size_t)n * sizeof(int);
    float* fused = (float*)(ws + off); off += (size_t)n * 7 * sizeof(float);
    float* sfused = (float*)(ws + off); off += nf;
    int* validArr = (int*)(ws + off); off += (size_t)n * sizeof(int);
    int* nclust = (int*)(ws + off); off += sizeof(int);

    prep_kernel<<<(n + 255) / 256, 256, 0, stream>>>(boxes, n, lox, loy, loz,
                                                     hix, hiy, hiz, vol, dir);
    adj_kernel<<<n, 256, 0, stream>>>(lox, loy, loz, hix, hiy, hiz, vol, adj, n, words);
    cluster_kernel<<<1, 64, 0, stream>>>(adj, indices, nclust, n, words);
    fusion_kernel<<<n, 256, 0, stream>>>(boxes, scores, indices, dir, nclust,
                                         fused, sfused, validArr, n);
    finalize_kernel<<<1, 1024, 0, stream>>>(fused, sfused, validArr, indices,
                                            (float*)d_out, n);
}